// Round 2
// baseline (1708.689 us; speedup 1.0000x reference)
//
#include <hip/hip_runtime.h>
#include <stdint.h>

typedef unsigned short u16;

__device__ __forceinline__ float bu2f(u16 u) {
  return __uint_as_float(((uint32_t)u) << 16);
}
__device__ __forceinline__ u16 f2bu(float f) {
  uint32_t u = __float_as_uint(f);
  u += 0x7fffu + ((u >> 16) & 1u);  // RNE
  return (u16)(u >> 16);
}

// ---- dtype abstraction ----------------------------------------------------
template <bool F32> struct In;
template <> struct In<true> {
  static __device__ __forceinline__ float ld(const void* p, long i) {
    return ((const float*)p)[i];
  }
  static __device__ __forceinline__ float4 ld4(const void* p, long i) {
    return *(const float4*)((const float*)p + i);  // i multiple of 4 at call sites
  }
};
template <> struct In<false> {
  static __device__ __forceinline__ float ld(const void* p, long i) {
    return bu2f(((const u16*)p)[i]);
  }
  static __device__ __forceinline__ float4 ld4(const void* p, long i) {
    ushort4 v = *(const ushort4*)((const u16*)p + i);
    return make_float4(bu2f(v.x), bu2f(v.y), bu2f(v.z), bu2f(v.w));
  }
};

template <bool F32> struct Mid;
template <> struct Mid<true> {
  static __device__ __forceinline__ float ld(const void* p, long i) {
    return ((const float*)p)[i];
  }
  static __device__ __forceinline__ void st(void* p, long i, float v) {
    ((float*)p)[i] = v;
  }
};
template <> struct Mid<false> {
  static __device__ __forceinline__ float ld(const void* p, long i) {
    return bu2f(((const u16*)p)[i]);
  }
  static __device__ __forceinline__ void st(void* p, long i, float v) {
    ((u16*)p)[i] = f2bu(v);
  }
};

// ---- dtype detector -------------------------------------------------------
// bf16 data: nearly all u16 exponent fields (bits 14:7) in [96,134].
// f32 data: low-half words have uniform bits there (~15% pass) -> ~57% total.
__global__ void k_detect(const u16* __restrict__ x, int* __restrict__ flag) {
  __shared__ int s[64];
  int cnt = 0;
  for (int i = threadIdx.x; i < 2048; i += 64) {
    int e = (x[i] >> 7) & 0xFF;
    cnt += (e >= 96 && e <= 134) ? 1 : 0;
  }
  s[threadIdx.x] = cnt;
  __syncthreads();
  if (threadIdx.x == 0) {
    int t = 0;
    for (int i = 0; i < 64; ++i) t += s[i];
    *flag = (t >= 1843) ? 0 : 1;  // 0 = bf16, 1 = f32
  }
}

// ---------------------------------------------------------------------------
// Kernel 1: conv1(5x5,3->6)+relu+pool2 + conv2(5x5,6->16)+relu+pool2
// One block per image; intermediates in LDS. Out p2: [B,400]
// ---------------------------------------------------------------------------
template <bool INF32, bool MIDF32>
__global__ __launch_bounds__(256) void k_conv(
    const int* __restrict__ flag,
    const void* __restrict__ x,
    const void* __restrict__ w1, const void* __restrict__ b1,
    const void* __restrict__ w2, const void* __restrict__ b2,
    void* __restrict__ p2) {
  if (*flag != (INF32 ? 1 : 0)) return;
  __shared__ float sx[3072];
  __shared__ float sw1[456];
  __shared__ float sw2[2416];
  __shared__ float sp1[1176];
  const int tid = threadIdx.x;
  const long img = blockIdx.x;
  for (int i = tid; i < 3072; i += 256) sx[i] = In<INF32>::ld(x, img * 3072 + i);
  for (int i = tid; i < 450; i += 256) sw1[i] = In<INF32>::ld(w1, i);
  if (tid < 6) sw1[450 + tid] = In<INF32>::ld(b1, tid);
  for (int i = tid; i < 2400; i += 256) sw2[i] = In<INF32>::ld(w2, i);
  if (tid < 16) sw2[2400 + tid] = In<INF32>::ld(b2, tid);
  __syncthreads();

  for (int o = tid; o < 1176; o += 256) {
    int c = o / 196, r = o - c * 196;
    int py = r / 14, px = r - py * 14;
    const float* wc = sw1 + c * 75;
    float m = 0.f;
#pragma unroll
    for (int dy = 0; dy < 2; ++dy) {
#pragma unroll
      for (int dx = 0; dx < 2; ++dx) {
        int y0 = 2 * py + dy, x0 = 2 * px + dx;
        float acc = sw1[450 + c];
#pragma unroll
        for (int ic = 0; ic < 3; ++ic) {
          const float* sp = sx + ic * 1024 + y0 * 32 + x0;
          const float* wp = wc + ic * 25;
#pragma unroll
          for (int ky = 0; ky < 5; ++ky)
#pragma unroll
            for (int kx = 0; kx < 5; ++kx)
              acc = fmaf(sp[ky * 32 + kx], wp[ky * 5 + kx], acc);
        }
        m = fmaxf(m, acc);
      }
    }
    sp1[o] = m;
  }
  __syncthreads();

  for (int o = tid; o < 400; o += 256) {
    int c = o / 25, r = o - c * 25;
    int py = r / 5, px = r - py * 5;
    const float* wc = sw2 + c * 150;
    float m = 0.f;
#pragma unroll
    for (int dy = 0; dy < 2; ++dy) {
#pragma unroll
      for (int dx = 0; dx < 2; ++dx) {
        int y0 = 2 * py + dy, x0 = 2 * px + dx;
        float acc = sw2[2400 + c];
#pragma unroll
        for (int ic = 0; ic < 6; ++ic) {
          const float* sp = sp1 + ic * 196 + y0 * 14 + x0;
          const float* wp = wc + ic * 25;
#pragma unroll
          for (int ky = 0; ky < 5; ++ky)
#pragma unroll
            for (int kx = 0; kx < 5; ++kx)
              acc = fmaf(sp[ky * 14 + kx], wp[ky * 5 + kx], acc);
        }
        m = fmaxf(m, acc);
      }
    }
    Mid<MIDF32>::st(p2, img * 400 + o, m);
  }
}

// ---------------------------------------------------------------------------
// Kernel 2: fc1 (400->120)+relu + fc2 (120->84)+relu. 8 tokens / block.
// ---------------------------------------------------------------------------
template <bool INF32, bool MIDF32>
__global__ __launch_bounds__(256) void k_fc(
    const int* __restrict__ flag,
    const void* __restrict__ p2,
    const void* __restrict__ w1, const void* __restrict__ b1,
    const void* __restrict__ w2, const void* __restrict__ b2,
    void* __restrict__ a2) {
  if (*flag != (INF32 ? 1 : 0)) return;
  __shared__ float sxin[8 * 400];
  __shared__ float sa1[8 * 120];
  const int tid = threadIdx.x;
  const long tok0 = (long)blockIdx.x * 8;
  for (int i = tid; i < 3200; i += 256) sxin[i] = Mid<MIDF32>::ld(p2, tok0 * 400 + i);
  __syncthreads();

  if (tid < 240) {
    int t = tid / 30, og = tid - (tid / 30) * 30;
    int o0 = og * 4;
    float4 bv = In<INF32>::ld4(b1, o0);
    float a0 = bv.x, a1v = bv.y, a2v = bv.z, a3 = bv.w;
    const float* xr = sxin + t * 400;
    for (int k = 0; k < 400; ++k) {
      float xv = xr[k];
      float4 wv = In<INF32>::ld4(w1, (long)k * 120 + o0);
      a0 = fmaf(xv, wv.x, a0);
      a1v = fmaf(xv, wv.y, a1v);
      a2v = fmaf(xv, wv.z, a2v);
      a3 = fmaf(xv, wv.w, a3);
    }
    float* ar = sa1 + t * 120 + o0;
    ar[0] = fmaxf(a0, 0.f); ar[1] = fmaxf(a1v, 0.f);
    ar[2] = fmaxf(a2v, 0.f); ar[3] = fmaxf(a3, 0.f);
  }
  __syncthreads();

  if (tid < 168) {
    int t = tid / 21, og = tid - (tid / 21) * 21;
    int o0 = og * 4;
    float4 bv = In<INF32>::ld4(b2, o0);
    float a0 = bv.x, a1v = bv.y, a2v = bv.z, a3 = bv.w;
    const float* xr = sa1 + t * 120;
    for (int k = 0; k < 120; ++k) {
      float xv = xr[k];
      float4 wv = In<INF32>::ld4(w2, (long)k * 84 + o0);
      a0 = fmaf(xv, wv.x, a0);
      a1v = fmaf(xv, wv.y, a1v);
      a2v = fmaf(xv, wv.z, a2v);
      a3 = fmaf(xv, wv.w, a3);
    }
    long ob = (tok0 + t) * 84 + o0;
    Mid<MIDF32>::st(a2, ob, fmaxf(a0, 0.f));
    Mid<MIDF32>::st(a2, ob + 1, fmaxf(a1v, 0.f));
    Mid<MIDF32>::st(a2, ob + 2, fmaxf(a2v, 0.f));
    Mid<MIDF32>::st(a2, ob + 3, fmaxf(a3, 0.f));
  }
}

// ---------------------------------------------------------------------------
// Kernel 3: gate softmax + both experts (84->2048->84) + combine + fc3(84->10)
// 16 tokens / block; hidden in 4 chunks of 512 (f32 in LDS).
// ---------------------------------------------------------------------------
template <bool INF32, bool MIDF32>
__global__ __launch_bounds__(256) void k_moe(
    const int* __restrict__ flag,
    const void* __restrict__ a2,
    const void* __restrict__ gw,
    const void* __restrict__ ew1, const void* __restrict__ eb1,
    const void* __restrict__ ew2, const void* __restrict__ eb2,
    const void* __restrict__ w3, const void* __restrict__ b3,
    void* __restrict__ out) {
  if (*flag != (INF32 ? 1 : 0)) return;
  __shared__ float sx[16 * 84];
  __shared__ float sh[16 * 512];
  __shared__ float sy[16 * 84];
  __shared__ float ssc[16 * 2];
  const int tid = threadIdx.x;
  const long tok0 = (long)blockIdx.x * 16;
  for (int i = tid; i < 16 * 84; i += 256) {
    sx[i] = Mid<MIDF32>::ld(a2, tok0 * 84 + i);
    sy[i] = 0.f;
  }
  __syncthreads();

  if (tid < 16) {
    const float* xr = sx + tid * 84;
    float l0 = 0.f, l1 = 0.f;
    for (int k = 0; k < 84; ++k) {
      float xv = xr[k];
      l0 = fmaf(xv, In<INF32>::ld(gw, 2 * k), l0);
      l1 = fmaf(xv, In<INF32>::ld(gw, 2 * k + 1), l1);
    }
    float m = fmaxf(l0, l1);
    float e0 = expf(l0 - m), e1 = expf(l1 - m);
    float inv = 1.f / (e0 + e1);
    ssc[tid * 2] = e0 * inv;
    ssc[tid * 2 + 1] = e1 * inv;
  }
  __syncthreads();

  for (int e = 0; e < 2; ++e) {
    const long w1off = (long)e * 84 * 2048;
    const long b1off = (long)e * 2048;
    const long w2off = (long)e * 2048 * 84;
    const long b2off = (long)e * 84;
    for (int ch = 0; ch < 4; ++ch) {
      const int jbase = ch * 512;
      // phase A: sh[16][512] = relu(x @ W1[:, jbase:+512] + b1)
      {
        int jg = tid & 127, tg = tid >> 7;
        int j0 = jbase + jg * 4, t0 = tg * 8;
        float4 bv = In<INF32>::ld4(eb1, b1off + j0);
        float acc[8][4];
#pragma unroll
        for (int tt = 0; tt < 8; ++tt) {
          acc[tt][0] = bv.x; acc[tt][1] = bv.y;
          acc[tt][2] = bv.z; acc[tt][3] = bv.w;
        }
        for (int k = 0; k < 84; ++k) {
          float4 wv = In<INF32>::ld4(ew1, w1off + (long)k * 2048 + j0);
#pragma unroll
          for (int tt = 0; tt < 8; ++tt) {
            float xv = sx[(t0 + tt) * 84 + k];
            acc[tt][0] = fmaf(xv, wv.x, acc[tt][0]);
            acc[tt][1] = fmaf(xv, wv.y, acc[tt][1]);
            acc[tt][2] = fmaf(xv, wv.z, acc[tt][2]);
            acc[tt][3] = fmaf(xv, wv.w, acc[tt][3]);
          }
        }
#pragma unroll
        for (int tt = 0; tt < 8; ++tt) {
          float* hp = sh + (t0 + tt) * 512 + jg * 4;
          hp[0] = fmaxf(acc[tt][0], 0.f);
          hp[1] = fmaxf(acc[tt][1], 0.f);
          hp[2] = fmaxf(acc[tt][2], 0.f);
          hp[3] = fmaxf(acc[tt][3], 0.f);
        }
      }
      __syncthreads();
      // phase B: sy += score_e * (h @ W2[jbase:+512, :] (+ b2 once))
      if (tid < 252) {
        int seg = tid / 42, rem = tid - seg * 42;
        int tg = rem / 21, dg = rem - tg * 21;
        int d0 = dg * 4, t0 = tg * 8;
        int j0 = (512 * seg) / 6, j1 = (512 * (seg + 1)) / 6;
        float bi0 = 0.f, bi1 = 0.f, bi2 = 0.f, bi3 = 0.f;
        if (ch == 0 && seg == 0) {
          float4 bv = In<INF32>::ld4(eb2, b2off + d0);
          bi0 = bv.x; bi1 = bv.y; bi2 = bv.z; bi3 = bv.w;
        }
        float acc[8][4];
#pragma unroll
        for (int tt = 0; tt < 8; ++tt) {
          acc[tt][0] = bi0; acc[tt][1] = bi1;
          acc[tt][2] = bi2; acc[tt][3] = bi3;
        }
        for (int jl = j0; jl < j1; ++jl) {
          float4 wv = In<INF32>::ld4(ew2, w2off + (long)(jbase + jl) * 84 + d0);
#pragma unroll
          for (int tt = 0; tt < 8; ++tt) {
            float hv = sh[(t0 + tt) * 512 + jl];
            acc[tt][0] = fmaf(hv, wv.x, acc[tt][0]);
            acc[tt][1] = fmaf(hv, wv.y, acc[tt][1]);
            acc[tt][2] = fmaf(hv, wv.z, acc[tt][2]);
            acc[tt][3] = fmaf(hv, wv.w, acc[tt][3]);
          }
        }
#pragma unroll
        for (int tt = 0; tt < 8; ++tt) {
          float sc = ssc[(t0 + tt) * 2 + e];
#pragma unroll
          for (int dd = 0; dd < 4; ++dd)
            atomicAdd(&sy[(t0 + tt) * 84 + d0 + dd], sc * acc[tt][dd]);
        }
      }
      __syncthreads();
    }
  }

  if (tid < 160) {
    int t = tid / 10, c = tid - (tid / 10) * 10;
    float acc = In<INF32>::ld(b3, c);
    const float* yr = sy + t * 84;
    for (int d = 0; d < 84; ++d)
      acc = fmaf(yr[d], In<INF32>::ld(w3, d * 10 + c), acc);
    long oi = (tok0 + t) * 10 + c;
    if (INF32) ((float*)out)[oi] = acc;
    else ((u16*)out)[oi] = f2bu(acc);
  }
}

// ---------------------------------------------------------------------------
template <bool MID>
static void launch_all(void* const* d_in, int B, void* d_out, void* d_ws,
                       hipStream_t stream) {
  char* wsb = (char*)d_ws;
  int* flag = (int*)wsb;
  void* p2 = wsb + 64;
  size_t p2_bytes = (size_t)B * 400 * (MID ? 4 : 2);
  void* a2 = wsb + 64 + p2_bytes;

  k_detect<<<1, 64, 0, stream>>>((const u16*)d_in[0], flag);

  k_conv<false, MID><<<B, 256, 0, stream>>>(flag, d_in[0], d_in[1], d_in[2],
                                            d_in[3], d_in[4], p2);
  k_conv<true, MID><<<B, 256, 0, stream>>>(flag, d_in[0], d_in[1], d_in[2],
                                           d_in[3], d_in[4], p2);
  k_fc<false, MID><<<B / 8, 256, 0, stream>>>(flag, p2, d_in[5], d_in[6],
                                              d_in[7], d_in[8], a2);
  k_fc<true, MID><<<B / 8, 256, 0, stream>>>(flag, p2, d_in[5], d_in[6],
                                             d_in[7], d_in[8], a2);
  k_moe<false, MID><<<B / 16, 256, 0, stream>>>(flag, a2, d_in[9], d_in[10],
                                                d_in[11], d_in[12], d_in[13],
                                                d_in[14], d_in[15], d_out);
  k_moe<true, MID><<<B / 16, 256, 0, stream>>>(flag, a2, d_in[9], d_in[10],
                                               d_in[11], d_in[12], d_in[13],
                                               d_in[14], d_in[15], d_out);
}

extern "C" void kernel_launch(void* const* d_in, const int* in_sizes, int n_in,
                              void* d_out, int out_size, void* d_ws, size_t ws_size,
                              hipStream_t stream) {
  const int B = in_sizes[0] / 3072;  // 16384
  size_t need_f32 = 64 + (size_t)B * 400 * 4 + (size_t)B * 84 * 4;
  if (ws_size >= need_f32) {
    launch_all<true>(d_in, B, d_out, d_ws, stream);
  } else {
    launch_all<false>(d_in, B, d_out, d_ws, stream);
  }
}

// Round 3
// 1007.784 us; speedup vs baseline: 1.6955x; 1.6955x over previous
//
#include <hip/hip_runtime.h>
#include <stdint.h>

typedef unsigned short u16;
typedef __attribute__((ext_vector_type(8))) short s8v;   // 8 x bf16 (4 VGPR)
typedef __attribute__((ext_vector_type(4))) float f4v;   // 4 x f32 acc

__device__ __forceinline__ float bu2f(u16 u) {
  return __uint_as_float(((uint32_t)u) << 16);
}
__device__ __forceinline__ u16 f2bu(float f) {
  uint32_t u = __float_as_uint(f);
  u += 0x7fffu + ((u >> 16) & 1u);  // RNE
  return (u16)(u >> 16);
}

// ---- input dtype abstraction (flag-selected at runtime) -------------------
template <bool F32> struct In;
template <> struct In<true> {
  static __device__ __forceinline__ float ld(const void* p, long i) {
    return ((const float*)p)[i];
  }
};
template <> struct In<false> {
  static __device__ __forceinline__ float ld(const void* p, long i) {
    return bu2f(((const u16*)p)[i]);
  }
};

// ---- dtype detector (unchanged from R2 — proven) --------------------------
__global__ void k_detect(const u16* __restrict__ x, int* __restrict__ flag) {
  __shared__ int s[64];
  int cnt = 0;
  for (int i = threadIdx.x; i < 2048; i += 64) {
    int e = (x[i] >> 7) & 0xFF;
    cnt += (e >= 96 && e <= 134) ? 1 : 0;
  }
  s[threadIdx.x] = cnt;
  __syncthreads();
  if (threadIdx.x == 0) {
    int t = 0;
    for (int i = 0; i < 64; ++i) t += s[i];
    *flag = (t >= 1843) ? 0 : 1;  // 0 = bf16, 1 = f32
  }
}

// ---------------------------------------------------------------------------
// Weight transpose/pad into ws (bf16), laid out [n][k] for MFMA B-fragments.
//  fc1t [128][416], fc2t [96][128], w1t [2][2048][96], w2t [2][96][2048]
// ---------------------------------------------------------------------------
template <bool INF32>
__global__ __launch_bounds__(256) void k_trans(
    const int* __restrict__ flag,
    const void* __restrict__ fc1w, const void* __restrict__ fc2w,
    const void* __restrict__ ew1, const void* __restrict__ ew2,
    u16* __restrict__ fc1t, u16* __restrict__ fc2t,
    u16* __restrict__ w1t, u16* __restrict__ w2t) {
  if (*flag != (INF32 ? 1 : 0)) return;
  long gid = (long)blockIdx.x * 256 + threadIdx.x;
  if (gid < 53248) {                       // fc1t: [128 n][416 k]
    int n = (int)(gid / 416), k = (int)(gid % 416);
    fc1t[gid] = (n < 120 && k < 400) ? f2bu(In<INF32>::ld(fc1w, (long)k * 120 + n)) : (u16)0;
  } else if (gid < 65536) {                // fc2t: [96 n][128 k]
    long i = gid - 53248;
    int n = (int)(i / 128), k = (int)(i % 128);
    fc2t[i] = (n < 84 && k < 120) ? f2bu(In<INF32>::ld(fc2w, (long)k * 84 + n)) : (u16)0;
  } else if (gid < 458752) {               // w1t: [2][2048 n][96 k]
    long i = gid - 65536;
    int e = (int)(i / 196608);
    long r = i % 196608;
    int n = (int)(r / 96), k = (int)(r % 96);
    w1t[i] = (k < 84) ? f2bu(In<INF32>::ld(ew1, ((long)e * 84 + k) * 2048 + n)) : (u16)0;
  } else if (gid < 851968) {               // w2t: [2][96 n][2048 k]
    long i = gid - 458752;
    int e = (int)(i / 196608);
    long r = i % 196608;
    int n = (int)(r / 2048), k = (int)(r % 2048);
    w2t[i] = (n < 84) ? f2bu(In<INF32>::ld(ew2, ((long)e * 2048 + k) * 84 + n)) : (u16)0;
  }
}

// ---------------------------------------------------------------------------
// Kernel 1: conv1+relu+pool + conv2+relu+pool. One block/image.
// Register 6x6 window shared across the 2x2 pool positions (~1/3 LDS reads).
// Out p2: [B][416] bf16, cols 400..415 zeroed (pre-padded K for fc1 MFMA).
// ---------------------------------------------------------------------------
template <bool INF32>
__global__ __launch_bounds__(256) void k_conv(
    const int* __restrict__ flag,
    const void* __restrict__ x,
    const void* __restrict__ w1, const void* __restrict__ b1,
    const void* __restrict__ w2, const void* __restrict__ b2,
    u16* __restrict__ p2) {
  if (*flag != (INF32 ? 1 : 0)) return;
  __shared__ float sx[3072];    // 3x32x32
  __shared__ float sw1[456];
  __shared__ float sw2[2416];
  __shared__ float sp1[1176];   // 6x14x14
  const int tid = threadIdx.x;
  const long img = blockIdx.x;
  for (int i = tid; i < 3072; i += 256) sx[i] = In<INF32>::ld(x, img * 3072 + i);
  for (int i = tid; i < 450; i += 256) sw1[i] = In<INF32>::ld(w1, i);
  if (tid < 6) sw1[450 + tid] = In<INF32>::ld(b1, tid);
  for (int i = tid; i < 2400; i += 256) sw2[i] = In<INF32>::ld(w2, i);
  if (tid < 16) sw2[2400 + tid] = In<INF32>::ld(b2, tid);
  __syncthreads();

  // conv1 + relu + maxpool -> sp1
  for (int o = tid; o < 1176; o += 256) {
    int c = o / 196, r = o - c * 196;
    int py = r / 14, px = r - py * 14;
    int y0 = 2 * py, x0 = 2 * px;
    const float* wc = sw1 + c * 75;
    float bias = sw1[450 + c];
    float a00 = bias, a01 = bias, a10 = bias, a11 = bias;
#pragma unroll
    for (int ic = 0; ic < 3; ++ic) {
      float win[6][6];
      const float* sp = sx + ic * 1024 + y0 * 32 + x0;
#pragma unroll
      for (int i = 0; i < 6; ++i)
#pragma unroll
        for (int j = 0; j < 6; ++j) win[i][j] = sp[i * 32 + j];
      const float* wp = wc + ic * 25;
#pragma unroll
      for (int ky = 0; ky < 5; ++ky)
#pragma unroll
        for (int kx = 0; kx < 5; ++kx) {
          float w = wp[ky * 5 + kx];
          a00 = fmaf(win[ky][kx], w, a00);
          a01 = fmaf(win[ky][kx + 1], w, a01);
          a10 = fmaf(win[ky + 1][kx], w, a10);
          a11 = fmaf(win[ky + 1][kx + 1], w, a11);
        }
    }
    sp1[o] = fmaxf(0.f, fmaxf(fmaxf(a00, a01), fmaxf(a10, a11)));
  }
  __syncthreads();

  // conv2 + relu + maxpool -> p2
  u16* pout = p2 + img * 416;
  for (int o = tid; o < 400; o += 256) {
    int c = o / 25, r = o - c * 25;
    int py = r / 5, px = r - py * 5;
    int y0 = 2 * py, x0 = 2 * px;
    const float* wc = sw2 + c * 150;
    float bias = sw2[2400 + c];
    float a00 = bias, a01 = bias, a10 = bias, a11 = bias;
#pragma unroll
    for (int ic = 0; ic < 6; ++ic) {
      float win[6][6];
      const float* sp = sp1 + ic * 196 + y0 * 14 + x0;
#pragma unroll
      for (int i = 0; i < 6; ++i)
#pragma unroll
        for (int j = 0; j < 6; ++j) win[i][j] = sp[i * 14 + j];
      const float* wp = wc + ic * 25;
#pragma unroll
      for (int ky = 0; ky < 5; ++ky)
#pragma unroll
        for (int kx = 0; kx < 5; ++kx) {
          float w = wp[ky * 5 + kx];
          a00 = fmaf(win[ky][kx], w, a00);
          a01 = fmaf(win[ky][kx + 1], w, a01);
          a10 = fmaf(win[ky + 1][kx], w, a10);
          a11 = fmaf(win[ky + 1][kx + 1], w, a11);
        }
    }
    pout[o] = f2bu(fmaxf(0.f, fmaxf(fmaxf(a00, a01), fmaxf(a10, a11))));
  }
  if (tid < 16) pout[400 + tid] = 0;  // zero K-pad for fc1
}

// ---------------------------------------------------------------------------
// Mega kernel: fc1 -> fc2 -> gate -> experts (both) -> combine -> fc3.
// 64 tokens/block, 4 waves (one 16-row strip each), mfma_f32_16x16x32_bf16.
// A-frag: lane m=ln&15, k=quad*8+j (row-major [m][k] LDS, stride padded).
// B-frag: lane n=ln&15, k=quad*8+j (transposed [n][k] LDS).
// C/D:    col=ln&15, row=quad*4+reg.
// ---------------------------------------------------------------------------
template <bool INF32>
__global__ __launch_bounds__(256) void k_mega(
    const int* __restrict__ flag,
    const u16* __restrict__ p2,
    const u16* __restrict__ fc1t, const u16* __restrict__ fc2t,
    const u16* __restrict__ w1t, const u16* __restrict__ w2t,
    const void* __restrict__ fc1b, const void* __restrict__ fc2b,
    const void* __restrict__ gw,
    const void* __restrict__ eb1, const void* __restrict__ eb2,
    const void* __restrict__ w3, const void* __restrict__ b3,
    void* __restrict__ out) {
  if (*flag != (INF32 ? 1 : 0)) return;
  __shared__ __align__(16) char smem[62976];
  u16* a2s = (u16*)smem;                    //  0      .. 13312  [64][104]
  u16* hs = (u16*)(smem + 13312);           // 13312   .. 30720  [64][136]
  float* ssc = (float*)(smem + 30720);      // 30720   .. 31232  [64][2]
  u16* wbuf = (u16*)(smem + 31232);         // 31232   .. 57856  (<=26624 B)
  u16* xs = (u16*)(smem + 57856);           // 57856   .. 62976  [64][40]
  float* ys = (float*)(smem + 31232);       // aliases wbuf: [64][96] f32

  const int tid = threadIdx.x;
  const int wv = tid >> 6, ln = tid & 63;
  const int m = ln & 15, quad = ln >> 4;
  const long t0 = (long)blockIdx.x * 64;
  const int row0 = wv * 16 + quad * 4;      // C/D rows for this lane: row0..+3

  // zero a2s + hs (pad columns must be 0)
  for (int i = tid; i < 30720 / 4; i += 256) ((uint32_t*)smem)[i] = 0;

  // ---------------- fc1: [64x416] @ [416->120pad128] ----------------
  f4v acc1[8];
#pragma unroll
  for (int i = 0; i < 8; ++i) acc1[i] = (f4v){0.f, 0.f, 0.f, 0.f};
  for (int s = 0; s < 13; ++s) {
    {  // stage x slice [64][32] -> xs[64][40]
      int r = tid >> 2, c0 = (tid & 3) * 8;
      *(uint4*)(xs + r * 40 + c0) =
          *(const uint4*)(p2 + (t0 + r) * 416 + s * 32 + c0);
      // stage w slice [128 n][32 k] -> wbuf[128][40]
      int n = tid >> 1, cw = (tid & 1) * 16;
      *(uint4*)(wbuf + n * 40 + cw) = *(const uint4*)(fc1t + (long)n * 416 + s * 32 + cw);
      *(uint4*)(wbuf + n * 40 + cw + 8) =
          *(const uint4*)(fc1t + (long)n * 416 + s * 32 + cw + 8);
    }
    __syncthreads();
    s8v a = *(const s8v*)(xs + (wv * 16 + m) * 40 + quad * 8);
#pragma unroll
    for (int nt = 0; nt < 8; ++nt) {
      s8v b = *(const s8v*)(wbuf + (nt * 16 + m) * 40 + quad * 8);
      acc1[nt] = __builtin_amdgcn_mfma_f32_16x16x32_bf16(a, b, acc1[nt], 0, 0, 0);
    }
    __syncthreads();
  }
#pragma unroll
  for (int nt = 0; nt < 8; ++nt) {
    int n = nt * 16 + m;
    if (n < 120) {
      float bv = In<INF32>::ld(fc1b, n);
#pragma unroll
      for (int r = 0; r < 4; ++r)
        hs[(row0 + r) * 136 + n] = f2bu(fmaxf(acc1[nt][r] + bv, 0.f));
    }
  }
  __syncthreads();

  // ---------------- fc2: [64x128] @ [128->84pad96] ----------------
  for (int i = tid; i < 1536; i += 256) {  // wbuf[96][136] <- fc2t[96][128]
    int n = i >> 4, c0 = (i & 15) * 8;
    *(uint4*)(wbuf + n * 136 + c0) = *(const uint4*)(fc2t + n * 128 + c0);
  }
  __syncthreads();
  f4v acc2[6];
#pragma unroll
  for (int i = 0; i < 6; ++i) acc2[i] = (f4v){0.f, 0.f, 0.f, 0.f};
  for (int s = 0; s < 4; ++s) {
    s8v a = *(const s8v*)(hs + (wv * 16 + m) * 136 + s * 32 + quad * 8);
#pragma unroll
    for (int nt = 0; nt < 6; ++nt) {
      s8v b = *(const s8v*)(wbuf + (nt * 16 + m) * 136 + s * 32 + quad * 8);
      acc2[nt] = __builtin_amdgcn_mfma_f32_16x16x32_bf16(a, b, acc2[nt], 0, 0, 0);
    }
  }
  __syncthreads();
#pragma unroll
  for (int nt = 0; nt < 6; ++nt) {
    int n = nt * 16 + m;
    if (n < 84) {
      float bv = In<INF32>::ld(fc2b, n);
#pragma unroll
      for (int r = 0; r < 4; ++r)
        a2s[(row0 + r) * 104 + n] = f2bu(fmaxf(acc2[nt][r] + bv, 0.f));
    }
  }
  __syncthreads();

  // ---------------- gate softmax (2 experts) ----------------
  if (tid < 64) {
    const u16* xr = a2s + tid * 104;
    float l0 = 0.f, l1 = 0.f;
    for (int k = 0; k < 84; ++k) {
      float xv = bu2f(xr[k]);
      l0 = fmaf(xv, In<INF32>::ld(gw, 2 * k), l0);
      l1 = fmaf(xv, In<INF32>::ld(gw, 2 * k + 1), l1);
    }
    float mx = fmaxf(l0, l1);
    float e0 = __expf(l0 - mx), e1 = __expf(l1 - mx);
    float inv = 1.f / (e0 + e1);
    ssc[tid * 2] = e0 * inv;
    ssc[tid * 2 + 1] = e1 * inv;
  }

  // ---------------- experts: h=relu(x@W1+b1); y+=sc*(h@W2+b2) ----------------
  f4v accy[6];
#pragma unroll
  for (int i = 0; i < 6; ++i) accy[i] = (f4v){0.f, 0.f, 0.f, 0.f};
  for (int e = 0; e < 2; ++e) {
    const u16* w1te = w1t + (long)e * 196608;
    const u16* w2te = w2t + (long)e * 196608;
    f4v acce[6];
#pragma unroll
    for (int i = 0; i < 6; ++i) acce[i] = (f4v){0.f, 0.f, 0.f, 0.f};
    for (int c = 0; c < 16; ++c) {
      const int n0 = c * 128;
      __syncthreads();  // previous wbuf consumers done
      for (int i = tid; i < 1536; i += 256) {  // wbuf[128][104] <- w1t chunk
        int nl = i / 12, c0 = (i % 12) * 8;
        *(uint4*)(wbuf + nl * 104 + c0) =
            *(const uint4*)(w1te + (long)(n0 + nl) * 96 + c0);
      }
      __syncthreads();
      // GEMM1: h chunk [64][128]
      f4v acch[8];
#pragma unroll
      for (int i = 0; i < 8; ++i) acch[i] = (f4v){0.f, 0.f, 0.f, 0.f};
      for (int s = 0; s < 3; ++s) {
        s8v a = *(const s8v*)(a2s + (wv * 16 + m) * 104 + s * 32 + quad * 8);
#pragma unroll
        for (int nt = 0; nt < 8; ++nt) {
          s8v b = *(const s8v*)(wbuf + (nt * 16 + m) * 104 + s * 32 + quad * 8);
          acch[nt] = __builtin_amdgcn_mfma_f32_16x16x32_bf16(a, b, acch[nt], 0, 0, 0);
        }
      }
#pragma unroll
      for (int nt = 0; nt < 8; ++nt) {
        float bv = In<INF32>::ld(eb1, (long)e * 2048 + n0 + nt * 16 + m);
#pragma unroll
        for (int r = 0; r < 4; ++r)
          hs[(row0 + r) * 136 + nt * 16 + m] = f2bu(fmaxf(acch[nt][r] + bv, 0.f));
      }
      __syncthreads();
      for (int i = tid; i < 1536; i += 256) {  // wbuf[96][136] <- w2t slice
        int n = i >> 4, c0 = (i & 15) * 8;
        *(uint4*)(wbuf + n * 136 + c0) =
            *(const uint4*)(w2te + (long)n * 2048 + n0 + c0);
      }
      __syncthreads();
      // GEMM2 partial: acce += h @ W2[n0:n0+128, :]
      for (int s = 0; s < 4; ++s) {
        s8v a = *(const s8v*)(hs + (wv * 16 + m) * 136 + s * 32 + quad * 8);
#pragma unroll
        for (int nt = 0; nt < 6; ++nt) {
          s8v b = *(const s8v*)(wbuf + (nt * 16 + m) * 136 + s * 32 + quad * 8);
          acce[nt] = __builtin_amdgcn_mfma_f32_16x16x32_bf16(a, b, acce[nt], 0, 0, 0);
        }
      }
    }
    // expert epilogue: accy += sc_row * (acce + b2)
    float sc[4];
#pragma unroll
    for (int r = 0; r < 4; ++r) sc[r] = ssc[(row0 + r) * 2 + e];
#pragma unroll
    for (int nt = 0; nt < 6; ++nt) {
      int d = nt * 16 + m;
      float bv = (d < 84) ? In<INF32>::ld(eb2, (long)e * 84 + d) : 0.f;
#pragma unroll
      for (int r = 0; r < 4; ++r) accy[nt][r] += sc[r] * (acce[nt][r] + bv);
    }
  }
  __syncthreads();  // all wbuf reads done; ys aliases wbuf
#pragma unroll
  for (int nt = 0; nt < 6; ++nt)
#pragma unroll
    for (int r = 0; r < 4; ++r) ys[(row0 + r) * 96 + nt * 16 + m] = accy[nt][r];
  __syncthreads();

  // ---------------- fc3: [64x84] @ [84x10] ----------------
  for (int idx = tid; idx < 640; idx += 256) {
    int tk = idx / 10, cc = idx - tk * 10;
    float acc = In<INF32>::ld(b3, cc);
    const float* yr = ys + tk * 96;
    for (int d = 0; d < 84; ++d)
      acc = fmaf(yr[d], In<INF32>::ld(w3, d * 10 + cc), acc);
    long oi = (t0 + tk) * 10 + cc;
    if (INF32) ((float*)out)[oi] = acc;
    else ((u16*)out)[oi] = f2bu(acc);
  }
}

// ---------------------------------------------------------------------------
extern "C" void kernel_launch(void* const* d_in, const int* in_sizes, int n_in,
                              void* d_out, int out_size, void* d_ws, size_t ws_size,
                              hipStream_t stream) {
  const int B = in_sizes[0] / 3072;  // 16384
  char* wsb = (char*)d_ws;
  int* flag = (int*)wsb;
  u16* p2 = (u16*)(wsb + 64);                    // [B][416] bf16
  u16* fc1t = p2 + (size_t)B * 416;              // 53248
  u16* fc2t = fc1t + 53248;                      // 12288
  u16* w1t = fc2t + 12288;                       // 393216
  u16* w2t = w1t + 393216;                       // 393216

  k_detect<<<1, 64, 0, stream>>>((const u16*)d_in[0], flag);

  k_trans<false><<<3328, 256, 0, stream>>>(flag, d_in[5], d_in[7], d_in[10],
                                           d_in[12], fc1t, fc2t, w1t, w2t);
  k_trans<true><<<3328, 256, 0, stream>>>(flag, d_in[5], d_in[7], d_in[10],
                                          d_in[12], fc1t, fc2t, w1t, w2t);

  k_conv<false><<<B, 256, 0, stream>>>(flag, d_in[0], d_in[1], d_in[2],
                                       d_in[3], d_in[4], p2);
  k_conv<true><<<B, 256, 0, stream>>>(flag, d_in[0], d_in[1], d_in[2],
                                      d_in[3], d_in[4], p2);

  k_mega<false><<<B / 64, 256, 0, stream>>>(flag, p2, fc1t, fc2t, w1t, w2t,
                                            d_in[6], d_in[8], d_in[9],
                                            d_in[11], d_in[13], d_in[14],
                                            d_in[15], d_out);
  k_mega<true><<<B / 64, 256, 0, stream>>>(flag, p2, fc1t, fc2t, w1t, w2t,
                                           d_in[6], d_in[8], d_in[9],
                                           d_in[11], d_in[13], d_in[14],
                                           d_in[15], d_out);
}

// Round 4
// 698.701 us; speedup vs baseline: 2.4455x; 1.4424x over previous
//
#include <hip/hip_runtime.h>
#include <stdint.h>

typedef unsigned short u16;
typedef __attribute__((ext_vector_type(8))) short s8v;   // 8 x bf16 (4 VGPR)
typedef __attribute__((ext_vector_type(4))) float f4v;   // 4 x f32 acc

__device__ __forceinline__ float bu2f(u16 u) {
  return __uint_as_float(((uint32_t)u) << 16);
}
__device__ __forceinline__ u16 f2bu(float f) {
  uint32_t u = __float_as_uint(f);
  u += 0x7fffu + ((u >> 16) & 1u);  // RNE
  return (u16)(u >> 16);
}

// ---- input dtype abstraction (flag-selected at runtime) -------------------
template <bool F32> struct In;
template <> struct In<true> {
  static __device__ __forceinline__ float ld(const void* p, long i) {
    return ((const float*)p)[i];
  }
};
template <> struct In<false> {
  static __device__ __forceinline__ float ld(const void* p, long i) {
    return bu2f(((const u16*)p)[i]);
  }
};

// ---- dtype detector (proven) ----------------------------------------------
__global__ void k_detect(const u16* __restrict__ x, int* __restrict__ flag) {
  __shared__ int s[64];
  int cnt = 0;
  for (int i = threadIdx.x; i < 2048; i += 64) {
    int e = (x[i] >> 7) & 0xFF;
    cnt += (e >= 96 && e <= 134) ? 1 : 0;
  }
  s[threadIdx.x] = cnt;
  __syncthreads();
  if (threadIdx.x == 0) {
    int t = 0;
    for (int i = 0; i < 64; ++i) t += s[i];
    *flag = (t >= 1843) ? 0 : 1;  // 0 = bf16, 1 = f32
  }
}

// ---------------------------------------------------------------------------
// Weight transpose/pad into ws. bf16 [n][k] for MFMA B-frags + f32 conv wts.
// ---------------------------------------------------------------------------
template <bool INF32>
__global__ __launch_bounds__(256) void k_trans(
    const int* __restrict__ flag,
    const void* __restrict__ fc1w, const void* __restrict__ fc2w,
    const void* __restrict__ ew1, const void* __restrict__ ew2,
    const void* __restrict__ c1w, const void* __restrict__ c1b,
    const void* __restrict__ c2w, const void* __restrict__ c2b,
    u16* __restrict__ fc1t, u16* __restrict__ fc2t,
    u16* __restrict__ w1t, u16* __restrict__ w2t,
    float* __restrict__ cwf) {
  if (*flag != (INF32 ? 1 : 0)) return;
  long gid = (long)blockIdx.x * 256 + threadIdx.x;
  if (gid < 53248) {                       // fc1t: [128 n][416 k]
    int n = (int)(gid / 416), k = (int)(gid % 416);
    fc1t[gid] = (n < 120 && k < 400) ? f2bu(In<INF32>::ld(fc1w, (long)k * 120 + n)) : (u16)0;
  } else if (gid < 65536) {                // fc2t: [96 n][128 k]
    long i = gid - 53248;
    int n = (int)(i / 128), k = (int)(i % 128);
    fc2t[i] = (n < 84 && k < 120) ? f2bu(In<INF32>::ld(fc2w, (long)k * 84 + n)) : (u16)0;
  } else if (gid < 458752) {               // w1t: [2][2048 n][96 k]
    long i = gid - 65536;
    int e = (int)(i / 196608);
    long r = i % 196608;
    int n = (int)(r / 96), k = (int)(r % 96);
    w1t[i] = (k < 84) ? f2bu(In<INF32>::ld(ew1, ((long)e * 84 + k) * 2048 + n)) : (u16)0;
  } else if (gid < 851968) {               // w2t: [2][96 n][2048 k]
    long i = gid - 458752;
    int e = (int)(i / 196608);
    long r = i % 196608;
    int n = (int)(r / 2048), k = (int)(r % 2048);
    w2t[i] = (n < 84) ? f2bu(In<INF32>::ld(ew2, ((long)e * 2048 + k) * 84 + n)) : (u16)0;
  } else if (gid < 854840) {               // conv weights -> f32
    long i = gid - 851968;
    if (i < 450) cwf[i] = In<INF32>::ld(c1w, i);
    else if (i < 456) cwf[i] = In<INF32>::ld(c1b, i - 450);
    else if (i < 2856) cwf[i] = In<INF32>::ld(c2w, i - 456);
    else cwf[i] = In<INF32>::ld(c2b, i - 2856);
  }
}

// ---------------------------------------------------------------------------
// Conv kernel v2: 5 images/block, one thread = one pooled output (all/4 chans)
// - windows shared across output channels (24x LDS-read reuse)
// - weights via uniform f32 global loads -> s_load (off the LDS pipe)
// - bf16 LDS, row strides 36 / 18 u16 (conflict-aware)
// Out p2: [B][416] bf16, cols 400..415 zero.
// ---------------------------------------------------------------------------
#define CIMG 5
template <bool INF32>
__global__ __launch_bounds__(256) void k_conv(
    const int* __restrict__ flag,
    const void* __restrict__ x,
    const float* __restrict__ cwf,   // [450 w1][6 b1][2400 w2][16 b2]
    u16* __restrict__ p2, int Btot) {
  if (*flag != (INF32 ? 1 : 0)) return;
  __shared__ u16 sxh[CIMG * 3 * 32 * 36];   // 34,560 B
  __shared__ u16 sp1h[CIMG * 6 * 14 * 18];  // 15,120 B
  const float* cw1 = cwf;
  const float* cw1b = cwf + 450;
  const float* cw2 = cwf + 456;
  const float* cw2b = cwf + 2856;
  const int tid = threadIdx.x;
  const long gimg0 = (long)blockIdx.x * CIMG;

  // ---- stage x -> bf16 LDS (row stride 36) ----
  for (int i = tid; i < CIMG * 96; i += 256) {  // i = img*96 + ic*32 + row
    int img = i / 96, rem = i - img * 96;
    if (gimg0 + img < Btot) {
      long goff = (gimg0 + img) * 3072 + (long)rem * 32;
      u16* dst = sxh + (size_t)i * 36;
      if (!INF32) {
        const u16* src = (const u16*)x + goff;
#pragma unroll
        for (int j = 0; j < 8; ++j)
          *(uint2*)(dst + j * 4) = *(const uint2*)(src + j * 4);
      } else {
        const float* src = (const float*)x + goff;
        for (int j = 0; j < 32; ++j) dst[j] = f2bu(src[j]);
      }
    }
  }
  __syncthreads();

  // ---- conv1 + relu + pool: task = (img, pooled pos), all 6 channels ----
  for (int task = tid; task < CIMG * 196; task += 256) {
    int img = task / 196, pos = task - img * 196;
    if (gimg0 + img >= Btot) continue;
    int py = pos / 14, px = pos - py * 14;
    float acc[6][4];
#pragma unroll
    for (int c = 0; c < 6; ++c) {
      float bv = cw1b[c];
      acc[c][0] = bv; acc[c][1] = bv; acc[c][2] = bv; acc[c][3] = bv;
    }
    for (int ic = 0; ic < 3; ++ic) {
      float win[6][6];
      const u16* base = sxh + ((size_t)(img * 3 + ic) * 32 + 2 * py) * 36 + 2 * px;
#pragma unroll
      for (int r = 0; r < 6; ++r) {
        uint32_t a = *(const uint32_t*)(base + r * 36);
        uint32_t b = *(const uint32_t*)(base + r * 36 + 2);
        uint32_t c2 = *(const uint32_t*)(base + r * 36 + 4);
        win[r][0] = __uint_as_float(a << 16);
        win[r][1] = __uint_as_float(a & 0xffff0000u);
        win[r][2] = __uint_as_float(b << 16);
        win[r][3] = __uint_as_float(b & 0xffff0000u);
        win[r][4] = __uint_as_float(c2 << 16);
        win[r][5] = __uint_as_float(c2 & 0xffff0000u);
      }
#pragma unroll
      for (int c = 0; c < 6; ++c) {
        const float* wp = cw1 + (c * 3 + ic) * 25;
#pragma unroll
        for (int ky = 0; ky < 5; ++ky)
#pragma unroll
          for (int kx = 0; kx < 5; ++kx) {
            float w = wp[ky * 5 + kx];
            acc[c][0] = fmaf(win[ky][kx], w, acc[c][0]);
            acc[c][1] = fmaf(win[ky][kx + 1], w, acc[c][1]);
            acc[c][2] = fmaf(win[ky + 1][kx], w, acc[c][2]);
            acc[c][3] = fmaf(win[ky + 1][kx + 1], w, acc[c][3]);
          }
      }
    }
#pragma unroll
    for (int c = 0; c < 6; ++c) {
      float m = fmaxf(0.f, fmaxf(fmaxf(acc[c][0], acc[c][1]),
                                 fmaxf(acc[c][2], acc[c][3])));
      sp1h[((size_t)(img * 6 + c) * 14 + py) * 18 + px] = f2bu(m);
    }
  }
  __syncthreads();

  // ---- conv2 + relu + pool: task = (img, ch-group of 4, pooled pos) ----
  for (int task = tid; task < CIMG * 100; task += 256) {
    int img = task / 100, r0 = task - img * 100;
    if (gimg0 + img >= Btot) continue;
    int grp = r0 / 25, pos = r0 - grp * 25;
    int py = pos / 5, px = pos - py * 5;
    int c0 = grp * 4;
    float acc[4][4];
#pragma unroll
    for (int c = 0; c < 4; ++c) {
      float bv = cw2b[c0 + c];
      acc[c][0] = bv; acc[c][1] = bv; acc[c][2] = bv; acc[c][3] = bv;
    }
    for (int ic = 0; ic < 6; ++ic) {
      float win[6][6];
      const u16* base = sp1h + ((size_t)(img * 6 + ic) * 14 + 2 * py) * 18 + 2 * px;
#pragma unroll
      for (int r = 0; r < 6; ++r) {
        uint32_t a = *(const uint32_t*)(base + r * 18);
        uint32_t b = *(const uint32_t*)(base + r * 18 + 2);
        uint32_t c2 = *(const uint32_t*)(base + r * 18 + 4);
        win[r][0] = __uint_as_float(a << 16);
        win[r][1] = __uint_as_float(a & 0xffff0000u);
        win[r][2] = __uint_as_float(b << 16);
        win[r][3] = __uint_as_float(b & 0xffff0000u);
        win[r][4] = __uint_as_float(c2 << 16);
        win[r][5] = __uint_as_float(c2 & 0xffff0000u);
      }
#pragma unroll
      for (int c = 0; c < 4; ++c) {
        const float* wp = cw2 + ((c0 + c) * 6 + ic) * 25;
#pragma unroll
        for (int ky = 0; ky < 5; ++ky)
#pragma unroll
          for (int kx = 0; kx < 5; ++kx) {
            float w = wp[ky * 5 + kx];
            acc[c][0] = fmaf(win[ky][kx], w, acc[c][0]);
            acc[c][1] = fmaf(win[ky][kx + 1], w, acc[c][1]);
            acc[c][2] = fmaf(win[ky + 1][kx], w, acc[c][2]);
            acc[c][3] = fmaf(win[ky + 1][kx + 1], w, acc[c][3]);
          }
      }
    }
    u16* pout = p2 + (gimg0 + img) * 416;
#pragma unroll
    for (int c = 0; c < 4; ++c) {
      float m = fmaxf(0.f, fmaxf(fmaxf(acc[c][0], acc[c][1]),
                                 fmaxf(acc[c][2], acc[c][3])));
      pout[(c0 + c) * 25 + py * 5 + px] = f2bu(m);
    }
  }

  // zero K-pad cols 400..415
  for (int i = tid; i < CIMG * 16; i += 256) {
    int img = i / 16;
    if (gimg0 + img < Btot) p2[(gimg0 + img) * 416 + 400 + (i & 15)] = 0;
  }
}

// ---------------------------------------------------------------------------
// Mega kernel (unchanged from R3 — proven): fc1->fc2->gate->experts->fc3.
// ---------------------------------------------------------------------------
template <bool INF32>
__global__ __launch_bounds__(256) void k_mega(
    const int* __restrict__ flag,
    const u16* __restrict__ p2,
    const u16* __restrict__ fc1t, const u16* __restrict__ fc2t,
    const u16* __restrict__ w1t, const u16* __restrict__ w2t,
    const void* __restrict__ fc1b, const void* __restrict__ fc2b,
    const void* __restrict__ gw,
    const void* __restrict__ eb1, const void* __restrict__ eb2,
    const void* __restrict__ w3, const void* __restrict__ b3,
    void* __restrict__ out) {
  if (*flag != (INF32 ? 1 : 0)) return;
  __shared__ __align__(16) char smem[62976];
  u16* a2s = (u16*)smem;                    // [64][104]
  u16* hs = (u16*)(smem + 13312);           // [64][136]
  float* ssc = (float*)(smem + 30720);      // [64][2]
  u16* wbuf = (u16*)(smem + 31232);
  u16* xs = (u16*)(smem + 57856);           // [64][40]
  float* ys = (float*)(smem + 31232);       // aliases wbuf: [64][96]

  const int tid = threadIdx.x;
  const int wv = tid >> 6, ln = tid & 63;
  const int m = ln & 15, quad = ln >> 4;
  const long t0 = (long)blockIdx.x * 64;
  const int row0 = wv * 16 + quad * 4;

  for (int i = tid; i < 30720 / 4; i += 256) ((uint32_t*)smem)[i] = 0;

  // fc1
  f4v acc1[8];
#pragma unroll
  for (int i = 0; i < 8; ++i) acc1[i] = (f4v){0.f, 0.f, 0.f, 0.f};
  for (int s = 0; s < 13; ++s) {
    {
      int r = tid >> 2, c0 = (tid & 3) * 8;
      *(uint4*)(xs + r * 40 + c0) =
          *(const uint4*)(p2 + (t0 + r) * 416 + s * 32 + c0);
      int n = tid >> 1, cw = (tid & 1) * 16;
      *(uint4*)(wbuf + n * 40 + cw) = *(const uint4*)(fc1t + (long)n * 416 + s * 32 + cw);
      *(uint4*)(wbuf + n * 40 + cw + 8) =
          *(const uint4*)(fc1t + (long)n * 416 + s * 32 + cw + 8);
    }
    __syncthreads();
    s8v a = *(const s8v*)(xs + (wv * 16 + m) * 40 + quad * 8);
#pragma unroll
    for (int nt = 0; nt < 8; ++nt) {
      s8v b = *(const s8v*)(wbuf + (nt * 16 + m) * 40 + quad * 8);
      acc1[nt] = __builtin_amdgcn_mfma_f32_16x16x32_bf16(a, b, acc1[nt], 0, 0, 0);
    }
    __syncthreads();
  }
#pragma unroll
  for (int nt = 0; nt < 8; ++nt) {
    int n = nt * 16 + m;
    if (n < 120) {
      float bv = In<INF32>::ld(fc1b, n);
#pragma unroll
      for (int r = 0; r < 4; ++r)
        hs[(row0 + r) * 136 + n] = f2bu(fmaxf(acc1[nt][r] + bv, 0.f));
    }
  }
  __syncthreads();

  // fc2
  for (int i = tid; i < 1536; i += 256) {
    int n = i >> 4, c0 = (i & 15) * 8;
    *(uint4*)(wbuf + n * 136 + c0) = *(const uint4*)(fc2t + n * 128 + c0);
  }
  __syncthreads();
  f4v acc2[6];
#pragma unroll
  for (int i = 0; i < 6; ++i) acc2[i] = (f4v){0.f, 0.f, 0.f, 0.f};
  for (int s = 0; s < 4; ++s) {
    s8v a = *(const s8v*)(hs + (wv * 16 + m) * 136 + s * 32 + quad * 8);
#pragma unroll
    for (int nt = 0; nt < 6; ++nt) {
      s8v b = *(const s8v*)(wbuf + (nt * 16 + m) * 136 + s * 32 + quad * 8);
      acc2[nt] = __builtin_amdgcn_mfma_f32_16x16x32_bf16(a, b, acc2[nt], 0, 0, 0);
    }
  }
  __syncthreads();
#pragma unroll
  for (int nt = 0; nt < 6; ++nt) {
    int n = nt * 16 + m;
    if (n < 84) {
      float bv = In<INF32>::ld(fc2b, n);
#pragma unroll
      for (int r = 0; r < 4; ++r)
        a2s[(row0 + r) * 104 + n] = f2bu(fmaxf(acc2[nt][r] + bv, 0.f));
    }
  }
  __syncthreads();

  // gate
  if (tid < 64) {
    const u16* xr = a2s + tid * 104;
    float l0 = 0.f, l1 = 0.f;
    for (int k = 0; k < 84; ++k) {
      float xv = bu2f(xr[k]);
      l0 = fmaf(xv, In<INF32>::ld(gw, 2 * k), l0);
      l1 = fmaf(xv, In<INF32>::ld(gw, 2 * k + 1), l1);
    }
    float mx = fmaxf(l0, l1);
    float e0 = __expf(l0 - mx), e1 = __expf(l1 - mx);
    float inv = 1.f / (e0 + e1);
    ssc[tid * 2] = e0 * inv;
    ssc[tid * 2 + 1] = e1 * inv;
  }

  // experts
  f4v accy[6];
#pragma unroll
  for (int i = 0; i < 6; ++i) accy[i] = (f4v){0.f, 0.f, 0.f, 0.f};
  for (int e = 0; e < 2; ++e) {
    const u16* w1te = w1t + (long)e * 196608;
    const u16* w2te = w2t + (long)e * 196608;
    f4v acce[6];
#pragma unroll
    for (int i = 0; i < 6; ++i) acce[i] = (f4v){0.f, 0.f, 0.f, 0.f};
    for (int c = 0; c < 16; ++c) {
      const int n0 = c * 128;
      __syncthreads();
      for (int i = tid; i < 1536; i += 256) {
        int nl = i / 12, c0 = (i % 12) * 8;
        *(uint4*)(wbuf + nl * 104 + c0) =
            *(const uint4*)(w1te + (long)(n0 + nl) * 96 + c0);
      }
      __syncthreads();
      f4v acch[8];
#pragma unroll
      for (int i = 0; i < 8; ++i) acch[i] = (f4v){0.f, 0.f, 0.f, 0.f};
      for (int s = 0; s < 3; ++s) {
        s8v a = *(const s8v*)(a2s + (wv * 16 + m) * 104 + s * 32 + quad * 8);
#pragma unroll
        for (int nt = 0; nt < 8; ++nt) {
          s8v b = *(const s8v*)(wbuf + (nt * 16 + m) * 104 + s * 32 + quad * 8);
          acch[nt] = __builtin_amdgcn_mfma_f32_16x16x32_bf16(a, b, acch[nt], 0, 0, 0);
        }
      }
#pragma unroll
      for (int nt = 0; nt < 8; ++nt) {
        float bv = In<INF32>::ld(eb1, (long)e * 2048 + n0 + nt * 16 + m);
#pragma unroll
        for (int r = 0; r < 4; ++r)
          hs[(row0 + r) * 136 + nt * 16 + m] = f2bu(fmaxf(acch[nt][r] + bv, 0.f));
      }
      __syncthreads();
      for (int i = tid; i < 1536; i += 256) {
        int n = i >> 4, c0 = (i & 15) * 8;
        *(uint4*)(wbuf + n * 136 + c0) =
            *(const uint4*)(w2te + (long)n * 2048 + n0 + c0);
      }
      __syncthreads();
      for (int s = 0; s < 4; ++s) {
        s8v a = *(const s8v*)(hs + (wv * 16 + m) * 136 + s * 32 + quad * 8);
#pragma unroll
        for (int nt = 0; nt < 6; ++nt) {
          s8v b = *(const s8v*)(wbuf + (nt * 16 + m) * 136 + s * 32 + quad * 8);
          acce[nt] = __builtin_amdgcn_mfma_f32_16x16x32_bf16(a, b, acce[nt], 0, 0, 0);
        }
      }
    }
    float sc[4];
#pragma unroll
    for (int r = 0; r < 4; ++r) sc[r] = ssc[(row0 + r) * 2 + e];
#pragma unroll
    for (int nt = 0; nt < 6; ++nt) {
      int d = nt * 16 + m;
      float bv = (d < 84) ? In<INF32>::ld(eb2, (long)e * 84 + d) : 0.f;
#pragma unroll
      for (int r = 0; r < 4; ++r) accy[nt][r] += sc[r] * (acce[nt][r] + bv);
    }
  }
  __syncthreads();
#pragma unroll
  for (int nt = 0; nt < 6; ++nt)
#pragma unroll
    for (int r = 0; r < 4; ++r) ys[(row0 + r) * 96 + nt * 16 + m] = accy[nt][r];
  __syncthreads();

  // fc3
  for (int idx = tid; idx < 640; idx += 256) {
    int tk = idx / 10, cc = idx - tk * 10;
    float acc = In<INF32>::ld(b3, cc);
    const float* yr = ys + tk * 96;
    for (int d = 0; d < 84; ++d)
      acc = fmaf(yr[d], In<INF32>::ld(w3, d * 10 + cc), acc);
    long oi = (t0 + tk) * 10 + cc;
    if (INF32) ((float*)out)[oi] = acc;
    else ((u16*)out)[oi] = f2bu(acc);
  }
}

// ---------------------------------------------------------------------------
extern "C" void kernel_launch(void* const* d_in, const int* in_sizes, int n_in,
                              void* d_out, int out_size, void* d_ws, size_t ws_size,
                              hipStream_t stream) {
  const int B = in_sizes[0] / 3072;  // 16384
  char* wsb = (char*)d_ws;
  int* flag = (int*)wsb;
  u16* p2 = (u16*)(wsb + 64);                    // [B][416] bf16
  u16* fc1t = p2 + (size_t)B * 416;              // 53248
  u16* fc2t = fc1t + 53248;                      // 12288
  u16* w1t = fc2t + 12288;                       // 393216
  u16* w2t = w1t + 393216;                       // 393216
  float* cwf = (float*)(w2t + 393216);           // 2872 f32 conv weights

  k_detect<<<1, 64, 0, stream>>>((const u16*)d_in[0], flag);

  k_trans<false><<<3340, 256, 0, stream>>>(flag, d_in[5], d_in[7], d_in[10],
                                           d_in[12], d_in[1], d_in[2], d_in[3],
                                           d_in[4], fc1t, fc2t, w1t, w2t, cwf);
  k_trans<true><<<3340, 256, 0, stream>>>(flag, d_in[5], d_in[7], d_in[10],
                                          d_in[12], d_in[1], d_in[2], d_in[3],
                                          d_in[4], fc1t, fc2t, w1t, w2t, cwf);

  const int convGrid = (B + CIMG - 1) / CIMG;
  k_conv<false><<<convGrid, 256, 0, stream>>>(flag, d_in[0], cwf, p2, B);
  k_conv<true><<<convGrid, 256, 0, stream>>>(flag, d_in[0], cwf, p2, B);

  k_mega<false><<<B / 64, 256, 0, stream>>>(flag, p2, fc1t, fc2t, w1t, w2t,
                                            d_in[6], d_in[8], d_in[9],
                                            d_in[11], d_in[13], d_in[14],
                                            d_in[15], d_out);
  k_mega<true><<<B / 64, 256, 0, stream>>>(flag, p2, fc1t, fc2t, w1t, w2t,
                                           d_in[6], d_in[8], d_in[9],
                                           d_in[11], d_in[13], d_in[14],
                                           d_in[15], d_out);
}

// Round 6
// 593.045 us; speedup vs baseline: 2.8812x; 1.1782x over previous
//
#include <hip/hip_runtime.h>
#include <stdint.h>

typedef unsigned short u16;
typedef __attribute__((ext_vector_type(8))) short s8v;    // 8 x bf16
typedef __attribute__((ext_vector_type(4))) float f4v;    // 4 x f32
typedef __fp16 h2v __attribute__((ext_vector_type(2)));   // 2 x f16

__device__ __forceinline__ float bu2f(u16 u) {
  return __uint_as_float(((uint32_t)u) << 16);
}
__device__ __forceinline__ u16 f2bu(float f) {
  uint32_t u = __float_as_uint(f);
  u += 0x7fffu + ((u >> 16) & 1u);  // RNE
  return (u16)(u >> 16);
}

union U32H2 { uint32_t u; h2v h; };

__device__ __forceinline__ uint32_t pk2h(float a, float b) {
  U32H2 x;
  x.h = __builtin_amdgcn_cvt_pkrtz(a, b);  // exact for bf16-valued inputs
  return x.u;
}

#if __has_builtin(__builtin_amdgcn_fdot2)
__device__ __forceinline__ float fdot2u(uint32_t a, uint32_t b, float c) {
  U32H2 ua, ub;
  ua.u = a; ub.u = b;
  return __builtin_amdgcn_fdot2(ua.h, ub.h, c, false);
}
#else
__device__ __forceinline__ float fdot2u(uint32_t a, uint32_t b, float c) {
  U32H2 ua, ub;
  ua.u = a; ub.u = b;
  c = fmaf((float)ua.h.x, (float)ub.h.x, c);
  return fmaf((float)ua.h.y, (float)ub.h.y, c);
}
#endif

// ---- input dtype abstraction ----------------------------------------------
template <bool F32> struct In;
template <> struct In<true> {
  static __device__ __forceinline__ float ld(const void* p, long i) {
    return ((const float*)p)[i];
  }
};
template <> struct In<false> {
  static __device__ __forceinline__ float ld(const void* p, long i) {
    return bu2f(((const u16*)p)[i]);
  }
};

// ---- dtype detector (proven) ----------------------------------------------
__global__ void k_detect(const u16* __restrict__ x, int* __restrict__ flag) {
  __shared__ int s[64];
  int cnt = 0;
  for (int i = threadIdx.x; i < 2048; i += 64) {
    int e = (x[i] >> 7) & 0xFF;
    cnt += (e >= 96 && e <= 134) ? 1 : 0;
  }
  s[threadIdx.x] = cnt;
  __syncthreads();
  if (threadIdx.x == 0) {
    int t = 0;
    for (int i = 0; i < 64; ++i) t += s[i];
    *flag = (t >= 1843) ? 0 : 1;  // 0 = bf16, 1 = f32
  }
}

// ---------------------------------------------------------------------------
// Weight transforms into ws:
//  fc1t [128][416] bf16, fc2t [96][128] bf16, w1t [2][2048][96] bf16,
//  w2t [2][96][2048] bf16, cdw: f16-pair packed conv weights + f32 biases.
// ---------------------------------------------------------------------------
__device__ __forceinline__ u16 f2h16(float f) {
  __fp16 h = (__fp16)f;
  u16 r;
  __builtin_memcpy(&r, &h, 2);
  return r;
}

template <bool INF32>
__global__ __launch_bounds__(256) void k_trans(
    const int* __restrict__ flag,
    const void* __restrict__ fc1w, const void* __restrict__ fc2w,
    const void* __restrict__ ew1, const void* __restrict__ ew2,
    const void* __restrict__ c1w, const void* __restrict__ c1b,
    const void* __restrict__ c2w, const void* __restrict__ c2b,
    u16* __restrict__ fc1t, u16* __restrict__ fc2t,
    u16* __restrict__ w1t, u16* __restrict__ w2t,
    uint32_t* __restrict__ cdw) {
  if (*flag != (INF32 ? 1 : 0)) return;
  long gid = (long)blockIdx.x * 256 + threadIdx.x;
  if (gid < 53248) {                       // fc1t: [128 n][416 k]
    int n = (int)(gid / 416), k = (int)(gid % 416);
    fc1t[gid] = (n < 120 && k < 400) ? f2bu(In<INF32>::ld(fc1w, (long)k * 120 + n)) : (u16)0;
  } else if (gid < 65536) {                // fc2t: [96 n][128 k]
    long i = gid - 53248;
    int n = (int)(i / 128), k = (int)(i % 128);
    fc2t[i] = (n < 84 && k < 120) ? f2bu(In<INF32>::ld(fc2w, (long)k * 84 + n)) : (u16)0;
  } else if (gid < 458752) {               // w1t: [2][2048 n][96 k]
    long i = gid - 65536;
    int e = (int)(i / 196608);
    long r = i % 196608;
    int n = (int)(r / 96), k = (int)(r % 96);
    w1t[i] = (k < 84) ? f2bu(In<INF32>::ld(ew1, ((long)e * 84 + k) * 2048 + n)) : (u16)0;
  } else if (gid < 851968) {               // w2t: [2][96 n][2048 k]
    long i = gid - 458752;
    int e = (int)(i / 196608);
    long r = i % 196608;
    int n = (int)(r / 2048), k = (int)(r % 2048);
    w2t[i] = (n < 84) ? f2bu(In<INF32>::ld(ew2, ((long)e * 2048 + k) * 84 + n)) : (u16)0;
  } else if (gid < 853700) {               // conv f16-pair weights + biases
    long i = gid - 851968;
    if (i < 270) {            // cd1: [6c][3ic][5ky][3p]
      int p = (int)(i % 3), ky = (int)((i / 3) % 5);
      int ic = (int)((i / 15) % 3), c = (int)(i / 45);
      long base = (((long)c * 3 + ic) * 5 + ky) * 5;
      float w0 = In<INF32>::ld(c1w, base + 2 * p);
      float w1 = (2 * p + 1 < 5) ? In<INF32>::ld(c1w, base + 2 * p + 1) : 0.f;
      cdw[i] = (uint32_t)f2h16(w0) | ((uint32_t)f2h16(w1) << 16);
    } else if (i < 1710) {    // cd2: [16c][6ic][5ky][3p]
      long j = i - 270;
      int p = (int)(j % 3), ky = (int)((j / 3) % 5);
      int ic = (int)((j / 15) % 6), c = (int)(j / 90);
      long base = (((long)c * 6 + ic) * 5 + ky) * 5;
      float w0 = In<INF32>::ld(c2w, base + 2 * p);
      float w1 = (2 * p + 1 < 5) ? In<INF32>::ld(c2w, base + 2 * p + 1) : 0.f;
      cdw[270 + j] = (uint32_t)f2h16(w0) | ((uint32_t)f2h16(w1) << 16);
    } else if (i < 1716) {    // cb1 (f32)
      ((float*)(cdw + 1710))[i - 1710] = In<INF32>::ld(c1b, i - 1710);
    } else if (i < 1732) {    // cb2 (f32)
      ((float*)(cdw + 1716))[i - 1716] = In<INF32>::ld(c2b, i - 1716);
    }
  }
}

// ---------------------------------------------------------------------------
// Conv kernel v3: f16 LDS + v_dot2_f32_f16 (2 MACs/inst, f32 accumulate).
// 5 images/block; aligned window dwords direct, shifted via alignbit.
// Out p2: [B][416] bf16, cols 400..415 zero.
// ---------------------------------------------------------------------------
#define CIMG 5
template <bool INF32>
__global__ __launch_bounds__(256) void k_conv(
    const int* __restrict__ flag,
    const void* __restrict__ x,
    const uint32_t* __restrict__ cdw,
    u16* __restrict__ p2, int Btot) {
  if (*flag != (INF32 ? 1 : 0)) return;
  __shared__ u16 sxh[CIMG * 3 * 32 * 36];   // f16, 34,560 B
  __shared__ u16 sp1h[CIMG * 6 * 14 * 18];  // f16, 15,120 B
  const uint32_t* cd1 = cdw;
  const uint32_t* cd2 = cdw + 270;
  const float* cb1 = (const float*)(cdw + 1710);
  const float* cb2 = (const float*)(cdw + 1716);
  const int tid = threadIdx.x;
  const long gimg0 = (long)blockIdx.x * CIMG;

  // zero pad columns (sxh cols 32..35, sp1h cols 14..17)
  for (int r = tid; r < CIMG * 96; r += 256) {
    *(uint32_t*)(sxh + (size_t)r * 36 + 32) = 0;
    *(uint32_t*)(sxh + (size_t)r * 36 + 34) = 0;
  }
  for (int r = tid; r < CIMG * 84; r += 256) {
    *(uint32_t*)(sp1h + (size_t)r * 18 + 14) = 0;
    *(uint32_t*)(sp1h + (size_t)r * 18 + 16) = 0;
  }

  // stage x -> f16 LDS
  for (int i = tid; i < CIMG * 96; i += 256) {
    int img = i / 96, rem = i - img * 96;
    if (gimg0 + img < Btot) {
      long goff = (gimg0 + img) * 3072 + (long)rem * 32;
      u16* dst = sxh + (size_t)i * 36;
      if (!INF32) {
        const uint32_t* src = (const uint32_t*)((const u16*)x + goff);
#pragma unroll
        for (int j = 0; j < 16; ++j) {
          uint32_t d = src[j];
          *(uint32_t*)(dst + 2 * j) =
              pk2h(__uint_as_float(d << 16), __uint_as_float(d & 0xffff0000u));
        }
      } else {
        const float* src = (const float*)x + goff;
#pragma unroll
        for (int j = 0; j < 16; ++j)
          *(uint32_t*)(dst + 2 * j) = pk2h(src[2 * j], src[2 * j + 1]);
      }
    }
  }
  __syncthreads();

  // conv1 + relu + pool: task = (img, pooled pos), all 6 channels
  for (int task = tid; task < CIMG * 196; task += 256) {
    int img = task / 196, pos = task - img * 196;
    if (gimg0 + img >= Btot) continue;
    int py = pos / 14, px = pos - py * 14;
    int x0 = 2 * px, y0 = 2 * py;
    float acc[6][4];
#pragma unroll
    for (int c = 0; c < 6; ++c) {
      float bv = cb1[c];
      acc[c][0] = bv; acc[c][1] = bv; acc[c][2] = bv; acc[c][3] = bv;
    }
    for (int ic = 0; ic < 3; ++ic) {
      uint32_t A[6][4], S[6][3];
      const u16* rb = sxh + ((size_t)(img * 3 + ic) * 32 + y0) * 36 + x0;
#pragma unroll
      for (int r = 0; r < 6; ++r) {
#pragma unroll
        for (int p = 0; p < 4; ++p)
          A[r][p] = *(const uint32_t*)(rb + (size_t)r * 36 + 2 * p);
#pragma unroll
        for (int p = 0; p < 3; ++p)
          S[r][p] = (A[r][p] >> 16) | (A[r][p + 1] << 16);
      }
#pragma unroll
      for (int c = 0; c < 6; ++c) {
        const uint32_t* wb = cd1 + ((c * 3 + ic) * 5) * 3;
#pragma unroll
        for (int ky = 0; ky < 5; ++ky) {
#pragma unroll
          for (int p = 0; p < 3; ++p) {
            uint32_t w = wb[ky * 3 + p];
            acc[c][0] = fdot2u(A[ky][p], w, acc[c][0]);
            acc[c][1] = fdot2u(S[ky][p], w, acc[c][1]);
            acc[c][2] = fdot2u(A[ky + 1][p], w, acc[c][2]);
            acc[c][3] = fdot2u(S[ky + 1][p], w, acc[c][3]);
          }
        }
      }
    }
#pragma unroll
    for (int c = 0; c < 6; ++c) {
      float m = fmaxf(0.f, fmaxf(fmaxf(acc[c][0], acc[c][1]),
                                 fmaxf(acc[c][2], acc[c][3])));
      sp1h[((size_t)(img * 6 + c) * 14 + py) * 18 + px] = f2h16(m);
    }
  }
  __syncthreads();

  // conv2 + relu + pool: task = (img, 4-channel group, pooled pos)
  for (int task = tid; task < CIMG * 100; task += 256) {
    int img = task / 100, r0 = task - img * 100;
    if (gimg0 + img >= Btot) continue;
    int grp = r0 / 25, pos = r0 - grp * 25;
    int py = pos / 5, px = pos - py * 5;
    int x0 = 2 * px, y0 = 2 * py;
    int c0 = grp * 4;
    float acc[4][4];
#pragma unroll
    for (int c = 0; c < 4; ++c) {
      float bv = cb2[c0 + c];
      acc[c][0] = bv; acc[c][1] = bv; acc[c][2] = bv; acc[c][3] = bv;
    }
    for (int ic = 0; ic < 6; ++ic) {
      uint32_t A[6][4], S[6][3];
      const u16* rb = sp1h + ((size_t)(img * 6 + ic) * 14 + y0) * 18 + x0;
#pragma unroll
      for (int r = 0; r < 6; ++r) {
#pragma unroll
        for (int p = 0; p < 4; ++p)
          A[r][p] = *(const uint32_t*)(rb + (size_t)r * 18 + 2 * p);
#pragma unroll
        for (int p = 0; p < 3; ++p)
          S[r][p] = (A[r][p] >> 16) | (A[r][p + 1] << 16);
      }
#pragma unroll
      for (int c = 0; c < 4; ++c) {
        const uint32_t* wb = cd2 + (((c0 + c) * 6 + ic) * 5) * 3;
#pragma unroll
        for (int ky = 0; ky < 5; ++ky) {
#pragma unroll
          for (int p = 0; p < 3; ++p) {
            uint32_t w = wb[ky * 3 + p];
            acc[c][0] = fdot2u(A[ky][p], w, acc[c][0]);
            acc[c][1] = fdot2u(S[ky][p], w, acc[c][1]);
            acc[c][2] = fdot2u(A[ky + 1][p], w, acc[c][2]);
            acc[c][3] = fdot2u(S[ky + 1][p], w, acc[c][3]);
          }
        }
      }
    }
    u16* pout = p2 + (gimg0 + img) * 416;
#pragma unroll
    for (int c = 0; c < 4; ++c) {
      float m = fmaxf(0.f, fmaxf(fmaxf(acc[c][0], acc[c][1]),
                                 fmaxf(acc[c][2], acc[c][3])));
      pout[(c0 + c) * 25 + py * 5 + px] = f2bu(m);
    }
  }

  for (int i = tid; i < CIMG * 16; i += 256) {
    int img = i / 16;
    if (gimg0 + img < Btot) p2[(gimg0 + img) * 416 + 400 + (i & 15)] = 0;
  }
}

// ---------------------------------------------------------------------------
// fcA: fc1 -> fc2 -> gate. 64 tokens/block; writes a2buf [B][104] bf16 +
// scbuf [B][2] f32. MFMA layouts as proven in R3.
// ---------------------------------------------------------------------------
template <bool INF32>
__global__ __launch_bounds__(256) void k_fcA(
    const int* __restrict__ flag,
    const u16* __restrict__ p2,
    const u16* __restrict__ fc1t, const u16* __restrict__ fc2t,
    const void* __restrict__ fc1b, const void* __restrict__ fc2b,
    const void* __restrict__ gw,
    u16* __restrict__ a2buf, float* __restrict__ scbuf) {
  if (*flag != (INF32 ? 1 : 0)) return;
  __shared__ __align__(16) char smem[62976];
  u16* a2s = (u16*)smem;                    // [64][104]
  u16* hs = (u16*)(smem + 13312);           // [64][136]
  u16* wbuf = (u16*)(smem + 31232);
  u16* xs = (u16*)(smem + 57856);           // [64][40]

  const int tid = threadIdx.x;
  const int wv = tid >> 6, ln = tid & 63;
  const int m = ln & 15, quad = ln >> 4;
  const long t0 = (long)blockIdx.x * 64;
  const int row0 = wv * 16 + quad * 4;

  for (int i = tid; i < 30720 / 4; i += 256) ((uint32_t*)smem)[i] = 0;

  // fc1
  f4v acc1[8];
#pragma unroll
  for (int i = 0; i < 8; ++i) acc1[i] = (f4v){0.f, 0.f, 0.f, 0.f};
  for (int s = 0; s < 13; ++s) {
    {
      int r = tid >> 2, c0 = (tid & 3) * 8;
      *(uint4*)(xs + r * 40 + c0) =
          *(const uint4*)(p2 + (t0 + r) * 416 + s * 32 + c0);
      int n = tid >> 1, cw = (tid & 1) * 16;
      *(uint4*)(wbuf + n * 40 + cw) = *(const uint4*)(fc1t + (long)n * 416 + s * 32 + cw);
      *(uint4*)(wbuf + n * 40 + cw + 8) =
          *(const uint4*)(fc1t + (long)n * 416 + s * 32 + cw + 8);
    }
    __syncthreads();
    s8v a = *(const s8v*)(xs + (wv * 16 + m) * 40 + quad * 8);
#pragma unroll
    for (int nt = 0; nt < 8; ++nt) {
      s8v b = *(const s8v*)(wbuf + (nt * 16 + m) * 40 + quad * 8);
      acc1[nt] = __builtin_amdgcn_mfma_f32_16x16x32_bf16(a, b, acc1[nt], 0, 0, 0);
    }
    __syncthreads();
  }
#pragma unroll
  for (int nt = 0; nt < 8; ++nt) {
    int n = nt * 16 + m;
    if (n < 120) {
      float bv = In<INF32>::ld(fc1b, n);
#pragma unroll
      for (int r = 0; r < 4; ++r)
        hs[(row0 + r) * 136 + n] = f2bu(fmaxf(acc1[nt][r] + bv, 0.f));
    }
  }
  __syncthreads();

  // fc2
  for (int i = tid; i < 1536; i += 256) {
    int n = i >> 4, c0 = (i & 15) * 8;
    *(uint4*)(wbuf + n * 136 + c0) = *(const uint4*)(fc2t + n * 128 + c0);
  }
  __syncthreads();
  f4v acc2[6];
#pragma unroll
  for (int i = 0; i < 6; ++i) acc2[i] = (f4v){0.f, 0.f, 0.f, 0.f};
  for (int s = 0; s < 4; ++s) {
    s8v a = *(const s8v*)(hs + (wv * 16 + m) * 136 + s * 32 + quad * 8);
#pragma unroll
    for (int nt = 0; nt < 6; ++nt) {
      s8v b = *(const s8v*)(wbuf + (nt * 16 + m) * 136 + s * 32 + quad * 8);
      acc2[nt] = __builtin_amdgcn_mfma_f32_16x16x32_bf16(a, b, acc2[nt], 0, 0, 0);
    }
  }
  __syncthreads();
#pragma unroll
  for (int nt = 0; nt < 6; ++nt) {
    int n = nt * 16 + m;
    if (n < 84) {
      float bv = In<INF32>::ld(fc2b, n);
#pragma unroll
      for (int r = 0; r < 4; ++r)
        a2s[(row0 + r) * 104 + n] = f2bu(fmaxf(acc2[nt][r] + bv, 0.f));
    }
  }
  __syncthreads();

  // gate + writeback
  if (tid < 64) {
    const u16* xr = a2s + tid * 104;
    float l0 = 0.f, l1 = 0.f;
    for (int k = 0; k < 84; ++k) {
      float xv = bu2f(xr[k]);
      l0 = fmaf(xv, In<INF32>::ld(gw, 2 * k), l0);
      l1 = fmaf(xv, In<INF32>::ld(gw, 2 * k + 1), l1);
    }
    float mx = fmaxf(l0, l1);
    float e0 = __expf(l0 - mx), e1 = __expf(l1 - mx);
    float inv = 1.f / (e0 + e1);
    *(float2*)(scbuf + (t0 + tid) * 2) = make_float2(e0 * inv, e1 * inv);
  }
  for (int i = tid; i < 832; i += 256) {  // 64 rows x 13 uint4
    int r = i / 13, c0 = (i - r * 13) * 8;
    *(uint4*)(a2buf + (t0 + r) * 104 + c0) = *(const uint4*)(a2s + r * 104 + c0);
  }
}

// ---------------------------------------------------------------------------
// exp: one expert per block (grid = [B/64, 2]) -> ybuf [2][B][96] f32.
// ---------------------------------------------------------------------------
template <bool INF32>
__global__ __launch_bounds__(256) void k_exp(
    const int* __restrict__ flag,
    const u16* __restrict__ a2buf, const float* __restrict__ scbuf,
    const u16* __restrict__ w1t, const u16* __restrict__ w2t,
    const void* __restrict__ eb1, const void* __restrict__ eb2,
    float* __restrict__ ybuf, int Btok) {
  if (*flag != (INF32 ? 1 : 0)) return;
  __shared__ __align__(16) char smem[57856];
  u16* a2s = (u16*)smem;                    // [64][104]
  u16* hs = (u16*)(smem + 13312);           // [64][136]
  u16* wbuf = (u16*)(smem + 30720);         // 26,624 B
  float* scs = (float*)(smem + 57344);      // [64]

  const int tid = threadIdx.x;
  const int wv = tid >> 6, ln = tid & 63;
  const int m = ln & 15, quad = ln >> 4;
  const int e = blockIdx.y;
  const long t0 = (long)blockIdx.x * 64;
  const int row0 = wv * 16 + quad * 4;
  const u16* w1te = w1t + (long)e * 196608;
  const u16* w2te = w2t + (long)e * 196608;

  for (int i = tid; i < 832; i += 256) {
    int r = i / 13, c0 = (i - r * 13) * 8;
    *(uint4*)(a2s + r * 104 + c0) = *(const uint4*)(a2buf + (t0 + r) * 104 + c0);
  }
  if (tid < 64) scs[tid] = scbuf[(t0 + tid) * 2 + e];
  __syncthreads();

  f4v acce[6];
#pragma unroll
  for (int i = 0; i < 6; ++i) acce[i] = (f4v){0.f, 0.f, 0.f, 0.f};
  for (int c = 0; c < 16; ++c) {
    const int n0 = c * 128;
    if (c) __syncthreads();
    for (int i = tid; i < 1536; i += 256) {  // wbuf[128][104] <- w1t chunk
      int nl = i / 12, c0 = (i - nl * 12) * 8;
      *(uint4*)(wbuf + nl * 104 + c0) =
          *(const uint4*)(w1te + (long)(n0 + nl) * 96 + c0);
    }
    __syncthreads();
    f4v acch[8];
#pragma unroll
    for (int i = 0; i < 8; ++i) acch[i] = (f4v){0.f, 0.f, 0.f, 0.f};
    for (int s = 0; s < 3; ++s) {
      s8v a = *(const s8v*)(a2s + (wv * 16 + m) * 104 + s * 32 + quad * 8);
#pragma unroll
      for (int nt = 0; nt < 8; ++nt) {
        s8v b = *(const s8v*)(wbuf + (nt * 16 + m) * 104 + s * 32 + quad * 8);
        acch[nt] = __builtin_amdgcn_mfma_f32_16x16x32_bf16(a, b, acch[nt], 0, 0, 0);
      }
    }
#pragma unroll
    for (int nt = 0; nt < 8; ++nt) {
      float bv = In<INF32>::ld(eb1, (long)e * 2048 + n0 + nt * 16 + m);
#pragma unroll
      for (int r = 0; r < 4; ++r)
        hs[(row0 + r) * 136 + nt * 16 + m] = f2bu(fmaxf(acch[nt][r] + bv, 0.f));
    }
    __syncthreads();
    for (int i = tid; i < 1536; i += 256) {  // wbuf[96][136] <- w2t slice
      int n = i >> 4, c0 = (i & 15) * 8;
      *(uint4*)(wbuf + n * 136 + c0) =
          *(const uint4*)(w2te + (long)n * 2048 + n0 + c0);
    }
    __syncthreads();
    for (int s = 0; s < 4; ++s) {
      s8v a = *(const s8v*)(hs + (wv * 16 + m) * 136 + s * 32 + quad * 8);
#pragma unroll
      for (int nt = 0; nt < 6; ++nt) {
        s8v b = *(const s8v*)(wbuf + (nt * 16 + m) * 136 + s * 32 + quad * 8);
        acce[nt] = __builtin_amdgcn_mfma_f32_16x16x32_bf16(a, b, acce[nt], 0, 0, 0);
      }
    }
  }

  // y_e = sc * (acce + b2) -> ybuf
#pragma unroll
  for (int nt = 0; nt < 6; ++nt) {
    int d = nt * 16 + m;
    float bv = (d < 84) ? In<INF32>::ld(eb2, (long)e * 84 + d) : 0.f;
#pragma unroll
    for (int r = 0; r < 4; ++r) {
      float sc = scs[row0 + r];
      ybuf[((size_t)e * Btok + t0 + row0 + r) * 96 + d] = sc * (acce[nt][r] + bv);
    }
  }
}

// ---------------------------------------------------------------------------
// fc3: out = (y0 + y1) @ w3 + b3. 64 tokens/block.
// ---------------------------------------------------------------------------
template <bool INF32>
__global__ __launch_bounds__(256) void k_fc3(
    const int* __restrict__ flag,
    const float* __restrict__ ybuf,
    const void* __restrict__ w3, const void* __restrict__ b3,
    void* __restrict__ out, int Btok) {
  if (*flag != (INF32 ? 1 : 0)) return;
  __shared__ float sw3[840];
  __shared__ float sb3[10];
  const int tid = threadIdx.x;
  const long t0 = (long)blockIdx.x * 64;
  for (int i = tid; i < 840; i += 256) sw3[i] = In<INF32>::ld(w3, i);
  if (tid < 10) sb3[tid] = In<INF32>::ld(b3, tid);
  __syncthreads();
  for (int idx = tid; idx < 640; idx += 256) {
    int tk = idx / 10, cc = idx - tk * 10;
    const float* y0r = ybuf + (t0 + tk) * 96;
    const float* y1r = ybuf + ((size_t)Btok + t0 + tk) * 96;
    float acc = sb3[cc];
    for (int d = 0; d < 84; ++d)
      acc = fmaf(y0r[d] + y1r[d], sw3[d * 10 + cc], acc);
    long oi = (t0 + tk) * 10 + cc;
    if (INF32) ((float*)out)[oi] = acc;
    else ((u16*)out)[oi] = f2bu(acc);
  }
}

// ---------------------------------------------------------------------------
extern "C" void kernel_launch(void* const* d_in, const int* in_sizes, int n_in,
                              void* d_out, int out_size, void* d_ws, size_t ws_size,
                              hipStream_t stream) {
  const int B = in_sizes[0] / 3072;  // 16384
  char* wsb = (char*)d_ws;
  int* flag = (int*)wsb;
  u16* p2 = (u16*)(wsb + 64);                    // [B][416] bf16
  u16* fc1t = p2 + (size_t)B * 416;              // 53,248 elems
  u16* fc2t = fc1t + 53248;                      // 12,288
  u16* w1t = fc2t + 12288;                       // 393,216
  u16* w2t = w1t + 393216;                       // 393,216
  uint32_t* cdw = (uint32_t*)(w2t + 393216);     // 1,732 dwords
  u16* a2buf = (u16*)(cdw + 1732);               // [B][104] bf16
  float* scbuf = (float*)(a2buf + (size_t)B * 104);  // [B][2] f32
  float* ybuf = scbuf + (size_t)B * 2;           // [2][B][96] f32

  k_detect<<<1, 64, 0, stream>>>((const u16*)d_in[0], flag);

  k_trans<false><<<3336, 256, 0, stream>>>(flag, d_in[5], d_in[7], d_in[10],
                                           d_in[12], d_in[1], d_in[2], d_in[3],
                                           d_in[4], fc1t, fc2t, w1t, w2t, cdw);
  k_trans<true><<<3336, 256, 0, stream>>>(flag, d_in[5], d_in[7], d_in[10],
                                          d_in[12], d_in[1], d_in[2], d_in[3],
                                          d_in[4], fc1t, fc2t, w1t, w2t, cdw);

  const int convGrid = (B + CIMG - 1) / CIMG;
  k_conv<false><<<convGrid, 256, 0, stream>>>(flag, d_in[0], cdw, p2, B);
  k_conv<true><<<convGrid, 256, 0, stream>>>(flag, d_in[0], cdw, p2, B);

  k_fcA<false><<<B / 64, 256, 0, stream>>>(flag, p2, fc1t, fc2t, d_in[6],
                                           d_in[8], d_in[9], a2buf, scbuf);
  k_fcA<true><<<B / 64, 256, 0, stream>>>(flag, p2, fc1t, fc2t, d_in[6],
                                          d_in[8], d_in[9], a2buf, scbuf);

  dim3 eg(B / 64, 2);
  k_exp<false><<<eg, 256, 0, stream>>>(flag, a2buf, scbuf, w1t, w2t, d_in[11],
                                       d_in[13], ybuf, B);
  k_exp<true><<<eg, 256, 0, stream>>>(flag, a2buf, scbuf, w1t, w2t, d_in[11],
                                      d_in[13], ybuf, B);

  k_fc3<false><<<B / 64, 256, 0, stream>>>(flag, ybuf, d_in[14], d_in[15],
                                           d_out, B);
  k_fc3<true><<<B / 64, 256, 0, stream>>>(flag, ybuf, d_in[14], d_in[15],
                                          d_out, B);
}